// Round 2
// baseline (484.242 us; speedup 1.0000x reference)
//
#include <hip/hip_runtime.h>
#include <math.h>

#define NBR    4        // NUM_BRANCHES
#define REP    1024     // REP_DIM
#define FD     128      // FEAT_DIM
#define NDATA  100000
#define KP1    4097     // NCE_K + 1
#define BN     128      // BATCH
#define MPN    0.04096f // m * Pn = 4096 / 100000
#define EPS_C  1e-7f
#define TINV   (1.0f / 0.07f)
#define NSLOT  64       // atomic slots (cachelines) for partial sums
#define TREFS  (BN * KP1)   // 524,416 total (b,k) refs
#define NWAVE  8192         // waves in k_pass1i (2048 blocks x 4)

typedef unsigned int   uint4e   __attribute__((ext_vector_type(4)));
typedef unsigned short ushort4e __attribute__((ext_vector_type(4)));
typedef _Float16       half2e   __attribute__((ext_vector_type(2)));
typedef float          floatx4  __attribute__((ext_vector_type(4)));

// ---------------------------------------------------------------------------
// fp16 / bf16 helpers
// ---------------------------------------------------------------------------
static __device__ __forceinline__ unsigned short f2h(float f) {
    union { _Float16 h; unsigned short u; } c; c.h = (_Float16)f; return c.u;
}
static __device__ __forceinline__ float h_lo(unsigned int u) {
    union { unsigned int u; _Float16 h[2]; } c; c.u = u; return (float)c.h[0];
}
static __device__ __forceinline__ float h_hi(unsigned int u) {
    union { unsigned int u; _Float16 h[2]; } c; c.u = u; return (float)c.h[1];
}
static __device__ __forceinline__ half2e u2h2(unsigned int u) {
    union { unsigned int u; half2e h; } c; c.u = u; return c.h;
}
static __device__ __forceinline__ unsigned short f2bf(float f) {
    union { float f; unsigned int u; } c; c.f = f;
    unsigned int u = c.u;
    u += 0x7fffu + ((u >> 16) & 1u);
    return (unsigned short)(u >> 16);
}
static __device__ __forceinline__ float bf2f(unsigned short h) {
    union { unsigned int u; float f; } c; c.u = ((unsigned int)h) << 16;
    return c.f;
}

// ---------------------------------------------------------------------------
// h[r,b,d] = sum_i emb_r[b,i] * W[r,d,i] + bias;  e = h/||h||
// Also emits f16 copy of e (layout [i][b][d]) for the inverted pass-1.
// grid (NBR, BN), block 128
// ---------------------------------------------------------------------------
__global__ void k_feat(const float* __restrict__ e0, const float* __restrict__ e1,
                       const float* __restrict__ e2, const float* __restrict__ e3,
                       const float* __restrict__ W, const float* __restrict__ bias,
                       float* __restrict__ e_out, ushort* __restrict__ eh16) {
    const int r = blockIdx.x;
    const int b = blockIdx.y;
    const float* emb = (r == 0 ? e0 : r == 1 ? e1 : r == 2 ? e2 : e3) + (size_t)b * REP;

    __shared__ float s_emb[REP];
    for (int i = threadIdx.x; i < REP; i += blockDim.x) s_emb[i] = emb[i];
    __syncthreads();

    const int d = threadIdx.x;
    const float4* wrow = (const float4*)(W + ((size_t)r * FD + d) * REP);
    float acc = 0.f;
#pragma unroll 8
    for (int c = 0; c < REP / 4; ++c) {
        float4 v = wrow[c];
        acc += v.x * s_emb[4*c+0] + v.y * s_emb[4*c+1]
             + v.z * s_emb[4*c+2] + v.w * s_emb[4*c+3];
    }
    float h = acc + bias[r * FD + d];

    __shared__ float red[FD];
    red[d] = h * h;
    __syncthreads();
    for (int off = FD / 2; off > 0; off >>= 1) {
        if (d < off) red[d] += red[d + off];
        __syncthreads();
    }
    float nrm = sqrtf(red[0]);
    float val = h / nrm;
    e_out[((size_t)r * BN + b) * FD + d] = val;
    if (eh16) eh16[((size_t)r * BN + b) * FD + d] = f2h(val);
}

// ---------------------------------------------------------------------------
// Inverted-index build.
// k_hist: counts[n] += 1 for every cidx entry.   grid (17, BN), block 256
// ---------------------------------------------------------------------------
__global__ void k_hist(const int* __restrict__ cidx, int* __restrict__ counts) {
    const int k = blockIdx.x * 256 + threadIdx.x;
    if (k >= KP1) return;
    const int b = blockIdx.y;
    atomicAdd(&counts[cidx[(size_t)b * KP1 + k]], 1);
}

// ---------------------------------------------------------------------------
// k_assign: start[n] = running offset of bucket n. Per-block exclusive scan
// (LDS) + one global atomic cursor per block. Bucket ORDER across blocks is
// nondeterministic; contents stay contiguous, which is all pass1 needs.
// grid 391, block 256.
// ---------------------------------------------------------------------------
__global__ void k_assign(const int* __restrict__ counts, int* __restrict__ start,
                         int* __restrict__ cursor) {
    __shared__ int s[256];
    __shared__ int sbase;
    const int tid = threadIdx.x;
    const int n = blockIdx.x * 256 + tid;
    int c = (n < NDATA) ? counts[n] : 0;
    s[tid] = c;
    __syncthreads();
#pragma unroll
    for (int off = 1; off < 256; off <<= 1) {
        int v = (tid >= off) ? s[tid - off] : 0;
        __syncthreads();
        s[tid] += v;
        __syncthreads();
    }
    if (tid == 255) sbase = atomicAdd(cursor, s[255]);
    __syncthreads();
    if (n < NDATA) start[n] = sbase + s[tid] - c;
}

// ---------------------------------------------------------------------------
// k_scatter: inv64[start[n] + pos] = (n<<20)|(b<<13)|k.  grid (17, BN).
// ---------------------------------------------------------------------------
__global__ void k_scatter(const int* __restrict__ cidx, const int* __restrict__ start,
                          int* __restrict__ fill, unsigned long long* __restrict__ inv64) {
    const int k = blockIdx.x * 256 + threadIdx.x;
    if (k >= KP1) return;
    const int b = blockIdx.y;
    const int n = cidx[(size_t)b * KP1 + k];
    const int pos = atomicAdd(&fill[n], 1);
    inv64[(size_t)start[n] + pos] =
        ((unsigned long long)(unsigned int)n << 20) |
        ((unsigned long long)(unsigned int)b << 13) |
        (unsigned long long)(unsigned int)k;
}

// ---------------------------------------------------------------------------
// Pass 1, INVERTED: stream fp32 memory exactly once instead of converting it
// (307 MB) and gathering 524 MB. Each wave walks a contiguous strip of the
// bucket-ordered ref list; on bucket change it loads the fp32 row (lane L:
// j=L>>4, d=(L&15)*8..+8, 32 B) and converts to f16 in-register (same RN
// rounding as the old k_convert_t). Per ref it gathers the L2-resident f16 e
// (4 x 16 B) and runs the EXACT fdot2 + folded-butterfly + exp + store
// sequence of the previous k_pass1w -> bit-identical per-(i,j,b,k) values.
// grid 2048, block 256 (NWAVE=8192 waves; 64 refs each, first 128 get 65).
// ---------------------------------------------------------------------------
__global__ __launch_bounds__(256)
void k_pass1i(const float* __restrict__ mem, const ushort* __restrict__ eh16,
              const unsigned long long* __restrict__ inv64,
              float* __restrict__ Zsl, ushort* __restrict__ expS) {
    const int lane = threadIdx.x & 63;
    const int w    = threadIdx.x >> 6;
    const int g    = (blockIdx.x << 2) + w;   // wave id [0, NWAVE)
    const int l4   = lane & 15;
    const int jj   = lane >> 4;
    const int d0   = l4 * 8;
    const bool b3  = (l4 & 8) != 0;
    const bool b2  = (l4 & 4) != 0;

    const int base = g * 64 + (g < 128 ? g : 128);
    const int end  = base + 64 + (g < 128 ? 1 : 0);

    const float* mrow_base = mem + (size_t)jj * NDATA * FD + d0;
    const ushort* eb_base  = eh16 + d0;

    float z = 0.f;
    int n_prev = -1;
    half2e mh[4];
    mh[0] = half2e{(_Float16)0.f, (_Float16)0.f};
    mh[1] = mh[0]; mh[2] = mh[0]; mh[3] = mh[0];

    unsigned long long vnext = inv64[base];
    for (int c = base; c < end; ++c) {
        const unsigned long long v = vnext;
        if (c + 1 < end) vnext = inv64[c + 1];
        const int n = (int)(v >> 20);
        const unsigned int bk = (unsigned int)v & 0xFFFFFu;
        const int b = (int)(bk >> 13);
        const int k = (int)(bk & 8191u);

        // issue e-gather early (L2-resident 128 KB), overlaps row load
        const ushort* eb = eb_base + (size_t)b * FD;
        uint4 ev0 = *(const uint4*)(eb);
        uint4 ev1 = *(const uint4*)(eb + (size_t)1 * BN * FD);
        uint4 ev2 = *(const uint4*)(eb + (size_t)2 * BN * FD);
        uint4 ev3 = *(const uint4*)(eb + (size_t)3 * BN * FD);

        if (n != n_prev) {   // wave-uniform branch, avg run length 5.24
            const floatx4* mp = (const floatx4*)(mrow_base + (size_t)n * FD);
            floatx4 v0 = __builtin_nontemporal_load(mp);
            floatx4 v1 = __builtin_nontemporal_load(mp + 1);
            mh[0] = half2e{(_Float16)v0.x, (_Float16)v0.y};
            mh[1] = half2e{(_Float16)v0.z, (_Float16)v0.w};
            mh[2] = half2e{(_Float16)v1.x, (_Float16)v1.y};
            mh[3] = half2e{(_Float16)v1.z, (_Float16)v1.w};
            n_prev = n;
        }

        float a0 = 0.f, a1 = 0.f, a2 = 0.f, a3 = 0.f;
#pragma unroll
        for (int q = 0; q < 4; ++q) {
            half2e hw = mh[q];
            a0 = __builtin_amdgcn_fdot2(hw, u2h2((&ev0.x)[q]), a0, false);
            a1 = __builtin_amdgcn_fdot2(hw, u2h2((&ev1.x)[q]), a1, false);
            a2 = __builtin_amdgcn_fdot2(hw, u2h2((&ev2.x)[q]), a2, false);
            a3 = __builtin_amdgcn_fdot2(hw, u2h2((&ev3.x)[q]), a3, false);
        }
        // folded butterfly within 16-lane j-group (identical to k_pass1w)
        float t0 = __shfl_xor(b3 ? a0 : a2, 8, 64);
        float t1 = __shfl_xor(b3 ? a1 : a3, 8, 64);
        float c0 = (b3 ? a2 : a0) + t0;
        float c1 = (b3 ? a3 : a1) + t1;
        float t2 = __shfl_xor(b2 ? c0 : c1, 4, 64);
        float d  = (b2 ? c1 : c0) + t2;
        d += __shfl_xor(d, 2, 64);
        d += __shfl_xor(d, 1, 64);
        // lane 16j+4i+r holds S_i summed over all 16 lanes of group j
        float x = __expf(d * TINV);
        z += x;
        if ((lane & 3) == 0)   // 16 leader lanes: 2B each, contiguous 32B/item
            expS[((size_t)b * KP1 + k) * 16 + (lane >> 2)] = f2h(x);
    }

    // cross-wave LDS reduce -> one coalesced 16-lane atomic per block
    __shared__ float s_z[4][16];   // [wave][i*4+j]
    const int i = ((l4 >> 3) << 1) | ((l4 >> 2) & 1);
    if ((lane & 3) == 0) s_z[w][i * 4 + jj] = z;
    __syncthreads();
    if (threadIdx.x < 16) {
        float vv = s_z[0][threadIdx.x] + s_z[1][threadIdx.x]
                 + s_z[2][threadIdx.x] + s_z[3][threadIdx.x];
        const int slot = blockIdx.x & (NSLOT - 1);
        atomicAdd(&Zsl[slot * 16 + threadIdx.x], vv);
    }
}

// ---------------------------------------------------------------------------
// Zsl[64][16] -> Zsum[16]  (layout [i*4+j])
// ---------------------------------------------------------------------------
__global__ void k_zred(const float* __restrict__ Zsl, float* __restrict__ Zsum) {
    if (threadIdx.x < 16) {
        float s = 0.f;
        for (int sl = 0; sl < NSLOT; ++sl) s += Zsl[sl * 16 + threadIdx.x];
        Zsum[threadIdx.x] = s;
    }
}

// ---------------------------------------------------------------------------
// Pass 2: stream expS ([b][k][j][i], f16, 32 B/item), accumulate 16 log-term
// sums. Slotted 16-lane atomics. grid (8, BN), block 256, 2 items/thread.
// ---------------------------------------------------------------------------
static __device__ __forceinline__ void acc_words(const uint4& p0, const uint4& p1,
                                                 const float* __restrict__ s_zinv,
                                                 float* __restrict__ acc, bool pos) {
    unsigned int wds[8] = {p0.x, p0.y, p0.z, p0.w, p1.x, p1.y, p1.z, p1.w};
#pragma unroll
    for (int w = 0; w < 8; ++w) {
        float v0 = h_lo(wds[w]) * s_zinv[2*w];
        float v1 = h_hi(wds[w]) * s_zinv[2*w+1];
        if (pos) {
            acc[2*w]   += -__logf(1.f + (MPN + EPS_C) / v0);
            acc[2*w+1] += -__logf(1.f + (MPN + EPS_C) / v1);
        } else {
            acc[2*w]   += -__logf(1.f + (v0 + EPS_C) * (1.f / MPN));
            acc[2*w+1] += -__logf(1.f + (v1 + EPS_C) * (1.f / MPN));
        }
    }
}

__global__ __launch_bounds__(256)
void k_pass2f(const uint4* __restrict__ expS, const float* __restrict__ Zsum,
              float* __restrict__ Asl) {
    const int b = blockIdx.y;

    __shared__ float s_zinv[16];   // [j*4+i]
    if (threadIdx.x < 16) {
        int jj = threadIdx.x >> 2, ii = threadIdx.x & 3;
        float Z = Zsum[ii * 4 + jj] *
                  (float)((double)NDATA / ((double)BN * (double)KP1));
        s_zinv[threadIdx.x] = 1.0f / Z;
    }
    __syncthreads();

    const uint4* es = expS + (size_t)b * (KP1 * 2);
    const int base = threadIdx.x + blockIdx.x * 256;   // [0, 2048)

    float acc[16];
#pragma unroll
    for (int t = 0; t < 16; ++t) acc[t] = 0.f;

#pragma unroll
    for (int it = 0; it < 2; ++it) {
        const int k = base + it * 2048;
        uint4 p0 = es[(size_t)k * 2];
        uint4 p1 = es[(size_t)k * 2 + 1];
        acc_words(p0, p1, s_zinv, acc, k == 0);
    }
    if (base == 0) {   // tail k = 4096
        uint4 p0 = es[(size_t)4096 * 2];
        uint4 p1 = es[(size_t)4096 * 2 + 1];
        acc_words(p0, p1, s_zinv, acc, false);
    }

#pragma unroll
    for (int t = 0; t < 16; ++t) {
#pragma unroll
        for (int off = 32; off > 0; off >>= 1)
            acc[t] += __shfl_down(acc[t], off, 64);
    }
    __shared__ float s_a[4][16];
    const int w = threadIdx.x >> 6;
    if ((threadIdx.x & 63) == 0) {
#pragma unroll
        for (int t = 0; t < 16; ++t) s_a[w][t] = acc[t];
    }
    __syncthreads();
    if (threadIdx.x < 16) {
        float v = s_a[0][threadIdx.x] + s_a[1][threadIdx.x]
                + s_a[2][threadIdx.x] + s_a[3][threadIdx.x];
        const int slot = (blockIdx.y * gridDim.x + blockIdx.x) & (NSLOT - 1);
        atomicAdd(&Asl[slot * 16 + threadIdx.x], v);
    }
}

// ---------------------------------------------------------------------------
// Asl[64][16] -> masked loss.  comp c = j*4+i; off-diag iff i != j.
// ---------------------------------------------------------------------------
__global__ void k_final_slots(const float* __restrict__ Asl, float* __restrict__ out) {
    const int tid = threadIdx.x;              // 256
    const int comp = tid & 15;
    const int grp  = tid >> 4;                // 16 groups
    float a = 0.f;
    for (int sl = grp; sl < NSLOT; sl += 16) a += Asl[sl * 16 + comp];
    const float m = ((comp >> 2) != (comp & 3)) ? 1.f : 0.f;
    __shared__ float s[256];
    s[tid] = a * m;
    __syncthreads();
    for (int off = 128; off > 0; off >>= 1) {
        if (tid < off) s[tid] += s[tid + off];
        __syncthreads();
    }
    if (tid == 0) out[0] = -s[0] / (float)BN;
}

// ---------------------------------------------------------------------------
// fp32 fallback pieces (only if workspace too small for the full path)
// ---------------------------------------------------------------------------
static __device__ __forceinline__ void dot4(const float4* __restrict__ row,
                                            const float* __restrict__ se,
                                            float& a0, float& a1, float& a2, float& a3) {
    a0 = a1 = a2 = a3 = 0.f;
#pragma unroll 8
    for (int c = 0; c < FD / 4; ++c) {
        float4 v = row[c];
        const int o = 4 * c;
        a0 += v.x * se[0*FD+o+0] + v.y * se[0*FD+o+1] + v.z * se[0*FD+o+2] + v.w * se[0*FD+o+3];
        a1 += v.x * se[1*FD+o+0] + v.y * se[1*FD+o+1] + v.z * se[1*FD+o+2] + v.w * se[1*FD+o+3];
        a2 += v.x * se[2*FD+o+0] + v.y * se[2*FD+o+1] + v.z * se[2*FD+o+2] + v.w * se[2*FD+o+3];
        a3 += v.x * se[3*FD+o+0] + v.y * se[3*FD+o+1] + v.z * se[3*FD+o+2] + v.w * se[3*FD+o+3];
    }
}

static __device__ __forceinline__ void block_reduce4(float z0, float z1, float z2,
                                                     float z3, float* dst, int j) {
    __shared__ float sred[256];
    float zs[NBR] = {z0, z1, z2, z3};
    for (int i = 0; i < NBR; ++i) {
        sred[threadIdx.x] = zs[i];
        __syncthreads();
        for (int off = 128; off > 0; off >>= 1) {
            if ((int)threadIdx.x < off) sred[threadIdx.x] += sred[threadIdx.x + off];
            __syncthreads();
        }
        if (threadIdx.x == 0) atomicAdd(&dst[i * NBR + j], sred[0]);
        __syncthreads();
    }
}

static __device__ __forceinline__ float term_of(float ex, float zinv, int k) {
    const float c = MPN + EPS_C;
    float v = ex * zinv;
    if (k == 0) return -__logf(1.0f + c / v);
    return -__logf(1.0f + (v + EPS_C) * (1.0f / MPN));
}

template <bool STORE>
__global__ void k_pass1_f32(const float* __restrict__ e, const float* __restrict__ memory,
                            const int* __restrict__ cidx,
                            float* __restrict__ Zsum, ushort4* __restrict__ expS) {
    const int j = blockIdx.z;
    const int b = blockIdx.y;

    __shared__ float s_e[NBR * FD];
    for (int t = threadIdx.x; t < NBR * FD; t += blockDim.x) {
        int i = t >> 7, d = t & (FD - 1);
        s_e[t] = e[((size_t)i * BN + b) * FD + d];
    }
    __syncthreads();

    const int* ci = cidx + (size_t)b * KP1;
    const float4* mem4 = (const float4*)(memory + (size_t)j * NDATA * FD);
    float z0 = 0.f, z1 = 0.f, z2 = 0.f, z3 = 0.f;

    for (int k = threadIdx.x + blockIdx.x * blockDim.x; k < KP1;
         k += blockDim.x * gridDim.x) {
        const int n = ci[k];
        const float4* row = mem4 + (size_t)n * (FD / 4);
        float a0, a1, a2, a3;
        dot4(row, s_e, a0, a1, a2, a3);
        float x0 = __expf(a0 * TINV);
        float x1 = __expf(a1 * TINV);
        float x2 = __expf(a2 * TINV);
        float x3 = __expf(a3 * TINV);
        z0 += x0; z1 += x1; z2 += x2; z3 += x3;
        if (STORE) {
            ushort4 st;
            st.x = f2bf(x0); st.y = f2bf(x1); st.z = f2bf(x2); st.w = f2bf(x3);
            expS[((size_t)j * BN + b) * KP1 + k] = st;
        }
    }
    block_reduce4(z0, z1, z2, z3, Zsum, j);
}

__global__ void k_pass2_stored(const ushort4* __restrict__ expS,
                               const float* __restrict__ Zsum,
                               float* __restrict__ accum) {
    const int j = blockIdx.z;
    const int b = blockIdx.y;

    __shared__ float s_zinv[NBR];
    if (threadIdx.x < NBR) {
        float Z = Zsum[threadIdx.x * NBR + j] *
                  (float)((double)NDATA / ((double)BN * (double)KP1));
        s_zinv[threadIdx.x] = 1.0f / Z;
    }
    __syncthreads();

    const ushort4* es = expS + ((size_t)j * BN + b) * KP1;
    float a0 = 0.f, a1 = 0.f, a2 = 0.f, a3 = 0.f;

    for (int k = threadIdx.x + blockIdx.x * blockDim.x; k < KP1;
         k += blockDim.x * gridDim.x) {
        ushort4 v = es[k];
        a0 += term_of(bf2f(v.x), s_zinv[0], k);
        a1 += term_of(bf2f(v.y), s_zinv[1], k);
        a2 += term_of(bf2f(v.z), s_zinv[2], k);
        a3 += term_of(bf2f(v.w), s_zinv[3], k);
    }
    block_reduce4(a0, a1, a2, a3, accum, j);
}

__global__ void k_pass2_regather(const float* __restrict__ e, const float* __restrict__ memory,
                                 const int* __restrict__ cidx,
                                 const float* __restrict__ Zsum, float* __restrict__ accum) {
    const int j = blockIdx.z;
    const int b = blockIdx.y;

    __shared__ float s_e[NBR * FD];
    __shared__ float s_zinv[NBR];
    for (int t = threadIdx.x; t < NBR * FD; t += blockDim.x) {
        int i = t >> 7, d = t & (FD - 1);
        s_e[t] = e[((size_t)i * BN + b) * FD + d];
    }
    if (threadIdx.x < NBR) {
        float Z = Zsum[threadIdx.x * NBR + j] *
                  (float)((double)NDATA / ((double)BN * (double)KP1));
        s_zinv[threadIdx.x] = 1.0f / Z;
    }
    __syncthreads();

    const int* ci = cidx + (size_t)b * KP1;
    const float4* mem4 = (const float4*)(memory + (size_t)j * NDATA * FD);
    float a0s = 0.f, a1s = 0.f, a2s = 0.f, a3s = 0.f;

    for (int k = threadIdx.x + blockIdx.x * blockDim.x; k < KP1;
         k += blockDim.x * gridDim.x) {
        const int n = ci[k];
        const float4* row = mem4 + (size_t)n * (FD / 4);
        float a0, a1, a2, a3;
        dot4(row, s_e, a0, a1, a2, a3);
        a0s += term_of(__expf(a0 * TINV), s_zinv[0], k);
        a1s += term_of(__expf(a1 * TINV), s_zinv[1], k);
        a2s += term_of(__expf(a2 * TINV), s_zinv[2], k);
        a3s += term_of(__expf(a3 * TINV), s_zinv[3], k);
    }
    block_reduce4(a0s, a1s, a2s, a3s, accum, j);
}

// ---------------------------------------------------------------------------
__global__ void k_init(float* __restrict__ p, int n) {
    int i = blockIdx.x * blockDim.x + threadIdx.x;
    if (i < n) p[i] = 0.f;
}

__global__ void k_final_legacy(const float* __restrict__ accum, float* __restrict__ out) {
    if (threadIdx.x == 0) {
        float s = 0.f;
        for (int i = 0; i < NBR; ++i)
            for (int j = 0; j < NBR; ++j)
                if (i != j) s += -accum[i * NBR + j] / (float)BN;
        out[0] = s;
    }
}

// ---------------------------------------------------------------------------
extern "C" void kernel_launch(void* const* d_in, const int* in_sizes, int n_in,
                              void* d_out, int out_size, void* d_ws, size_t ws_size,
                              hipStream_t stream) {
    const float* e0   = (const float*)d_in[0];
    const float* e1   = (const float*)d_in[1];
    const float* e2   = (const float*)d_in[2];
    const float* e3   = (const float*)d_in[3];
    const float* W    = (const float*)d_in[4];
    const float* bias = (const float*)d_in[5];
    const float* mem  = (const float*)d_in[6];
    const int*   cidx = (const int*)d_in[8];
    float* out = (float*)d_out;

    // ws (floats): e[65536] | Zsum[16] | accum[16] | Zsl[1024] | Asl[1024]
    // then (bytes, 16-aligned): eh16 | counts | fill | cursor | start | inv64 | expS
    float* ws    = (float*)d_ws;
    float* e     = ws;
    float* Zsum  = ws + 65536;
    float* accum = ws + 65552;
    float* Zsl   = ws + 65568;
    float* Asl   = ws + 66592;
    const size_t base_b   = (size_t)67616 * 4;               // 270,464 B
    const size_t eh16_b   = (size_t)NBR * BN * FD * 2;       // 131,072 B
    const size_t cnt_b    = (size_t)NDATA * 4;               // 400,000 B
    const size_t cur_b    = 16;                              // cursor (padded)
    const size_t inv_b    = (size_t)TREFS * 8;               // 4,195,328 B
    const size_t expS_b   = (size_t)BN * KP1 * 16 * 2;       // 16,781,312 B

    const size_t off_eh16   = base_b;
    const size_t off_counts = off_eh16 + eh16_b;
    const size_t off_fill   = off_counts + cnt_b;
    const size_t off_cursor = off_fill + cnt_b;
    const size_t off_start  = off_cursor + cur_b;
    const size_t off_inv    = off_start + cnt_b;
    const size_t off_expS   = off_inv + inv_b;

    const size_t need_full = off_expS + expS_b;              // ~22.6 MB
    const size_t need_mid  = base_b + expS_b;                // ~17.05 MB

    if (ws_size >= need_full) {
        ushort* eh16 = (ushort*)((char*)d_ws + off_eh16);
        int* counts  = (int*)((char*)d_ws + off_counts);
        int* fill    = (int*)((char*)d_ws + off_fill);
        int* cursor  = (int*)((char*)d_ws + off_cursor);
        int* start   = (int*)((char*)d_ws + off_start);
        unsigned long long* inv64 = (unsigned long long*)((char*)d_ws + off_inv);
        ushort* expS = (ushort*)((char*)d_ws + off_expS);

        k_init<<<9, 256, 0, stream>>>(Zsum, 2080);            // Zsum+accum+Zsl+Asl
        k_init<<<782, 256, 0, stream>>>((float*)counts, 200004); // counts+fill+cursor
        k_feat<<<dim3(NBR, BN), 128, 0, stream>>>(e0, e1, e2, e3, W, bias, e, eh16);
        k_hist<<<dim3(17, BN), 256, 0, stream>>>(cidx, counts);
        k_assign<<<391, 256, 0, stream>>>(counts, start, cursor);
        k_scatter<<<dim3(17, BN), 256, 0, stream>>>(cidx, start, fill, inv64);
        k_pass1i<<<2048, 256, 0, stream>>>(mem, eh16, inv64, Zsl, expS);
        k_zred<<<1, 64, 0, stream>>>(Zsl, Zsum);
        k_pass2f<<<dim3(8, BN), 256, 0, stream>>>((const uint4*)expS, Zsum, Asl);
        k_final_slots<<<1, 256, 0, stream>>>(Asl, out);
    } else if (ws_size >= need_mid) {
        k_init<<<9, 256, 0, stream>>>(Zsum, 2080);
        k_feat<<<dim3(NBR, BN), 128, 0, stream>>>(e0, e1, e2, e3, W, bias, e, nullptr);
        ushort4* expS = (ushort4*)((char*)d_ws + base_b);
        k_pass1_f32<true><<<dim3(4, BN, NBR), 256, 0, stream>>>(e, mem, cidx, Zsum, expS);
        k_pass2_stored<<<dim3(4, BN, NBR), 256, 0, stream>>>(expS, Zsum, accum);
        k_final_legacy<<<1, 64, 0, stream>>>(accum, out);
    } else {
        k_init<<<9, 256, 0, stream>>>(Zsum, 2080);
        k_feat<<<dim3(NBR, BN), 128, 0, stream>>>(e0, e1, e2, e3, W, bias, e, nullptr);
        k_pass1_f32<false><<<dim3(4, BN, NBR), 256, 0, stream>>>(e, mem, cidx, Zsum, nullptr);
        k_pass2_regather<<<dim3(4, BN, NBR), 256, 0, stream>>>(e, mem, cidx, Zsum, accum);
        k_final_legacy<<<1, 64, 0, stream>>>(accum, out);
    }
}